// Round 15
// baseline (1035.299 us; speedup 1.0000x reference)
//
#include <hip/hip_runtime.h>
#include <hip/hip_bf16.h>

#define NV 3
#define NPTS 32768
#define C2C 256
#define C3C 32
#define CINC 288
#define CINP 320
#define HH 128
#define WWW 128
#define DDD 32

typedef short bh8 __attribute__((ext_vector_type(8)));
typedef float fx4 __attribute__((ext_vector_type(4)));
typedef unsigned short us4 __attribute__((ext_vector_type(4)));

__device__ __forceinline__ float b2f(unsigned short u) {
    unsigned int x = ((unsigned int)u) << 16;
    return __uint_as_float(x);
}
__device__ __forceinline__ unsigned short f2b(float f) {
    unsigned int x = __float_as_uint(f);
    unsigned int r = (x + 0x7FFFu + ((x >> 16) & 1u)) >> 16;
    return (unsigned short)r;
}

__device__ __forceinline__ void gl2lds16(const unsigned short* g, unsigned short* l) {
    __builtin_amdgcn_global_load_lds(
        (const __attribute__((address_space(1))) unsigned int*)g,
        (__attribute__((address_space(3))) unsigned int*)l, 16, 0, 0);
}

// L2-pairing block decode (requires n-panels % 8 == 0)
template <int MB>
__device__ __forceinline__ void pair_decode(int b, int& mIdx, int& nIdx) {
    constexpr int L = (MB == 1) ? 0 : (MB == 2) ? 1 : 2;
    nIdx = ((b >> (3 + L)) << 3) | (b & 7);
    mIdx = (b >> 3) & (MB - 1);
}

// ---------------- merged prep: weight pad-cast + img transpose + vol transpose ----------------
__global__ __launch_bounds__(256) void k_prep(
    const float* __restrict__ s0, const float* __restrict__ s1,
    const float* __restrict__ s2, const float* __restrict__ s3,
    unsigned short* __restrict__ d0, unsigned short* __restrict__ d1,
    unsigned short* __restrict__ d2, unsigned short* __restrict__ d3,
    const float* __restrict__ img0, const float* __restrict__ img1,
    unsigned short* __restrict__ imgT, size_t imgStride,
    const float* __restrict__ vol0, const float* __restrict__ vol1,
    unsigned short* __restrict__ volT, size_t volStride) {
    __shared__ float smem[32 * 257];
    int b = blockIdx.x;
    if (b < 5088) {
        int base, M, Kp;
        const float* src;
        unsigned short* dst;
        if (b < 1280)      { base = 0;    M = 1024; Kp = 320;  src = s0; dst = d0; }
        else if (b < 3968) { base = 1280; M = 512;  Kp = 1344; src = s1; dst = d1; }
        else if (b < 4800) { base = 3968; M = 256;  Kp = 832;  src = s2; dst = d2; }
        else               { base = 4800; M = 128;  Kp = 576;  src = s3; dst = d3; }
        int idx = (b - base) * 256 + threadIdx.x;
        if (idx >= M * Kp) return;
        int m = idx / Kp, k = idx - m * Kp;
        int Ksrc = Kp - 32;
        float v;
        if (k < CINC) v = src[(size_t)m * Ksrc + k];
        else if (k < CINP) v = 0.0f;
        else v = src[(size_t)m * Ksrc + (k - 32)];
        dst[idx] = f2b(v);
    } else if (b < 11232) {
        int id = b - 5088;
        int bx = id % 384, by = (id / 384) & 1, bz = id / 768;
        int lvl = bz >> 2, cb = bz & 3;
        const float* in = lvl ? img1 : img0;
        int v = bx >> 7, y = bx & 127;
        int x0 = by << 6, c0 = cb << 6;
        float (*t)[65] = (float(*)[65])smem;
        int tx = threadIdx.x & 63, tg = threadIdx.x >> 6;
        const float* src = in + (((size_t)(v * C2C + c0) * HH + y) * WWW + x0);
#pragma unroll
        for (int i = 0; i < 16; i++) {
            int cl = tg * 16 + i;
            t[cl][tx] = src[(size_t)cl * (HH * WWW) + tx];
        }
        __syncthreads();
        unsigned short* dst = imgT + lvl * imgStride + ((size_t)(v * HH + y) * WWW + x0) * C2C + c0;
#pragma unroll
        for (int i = 0; i < 16; i++) {
            int xl = tg * 16 + i;
            dst[(size_t)xl * C2C + tx] = f2b(t[tx][xl]);
        }
    } else {
        int id = b - 11232;
        int v = id % 3, sy = (id / 3) & 127, lvl = id / 384;
        const float* in = lvl ? vol1 : vol0;
        int s0i = sy << 8;
        float (*t)[257] = (float(*)[257])smem;
        int tid = threadIdx.x;
        const float* src = in + (size_t)v * C3C * 32768 + s0i;
#pragma unroll
        for (int c = 0; c < 32; c++) t[c][tid] = src[(size_t)c * 32768 + tid];
        __syncthreads();
        unsigned short* dst = volT + lvl * volStride + ((size_t)v * 32768 + s0i) * C3C;
        int c = tid & 31, sb = tid >> 5;
#pragma unroll
        for (int j = 0; j < 32; j++) {
            int sl = j * 8 + sb;
            dst[(size_t)sl * C3C + c] = f2b(t[c][sl]);
        }
    }
}

// ---------------- sampler body: wave per (point,view) ----------------
__device__ __forceinline__ void sample_body(const float* __restrict__ pts, const float* __restrict__ proj,
                         const unsigned short* __restrict__ imgT, const unsigned short* __restrict__ volT,
                         unsigned short* __restrict__ ptT, int n0, int Nk) {
    int w = threadIdx.x >> 6, l = threadIdx.x & 63;
    int i = blockIdx.x * 4 + w;
    int v = blockIdx.y;
    int n = n0 + i;
    unsigned short* dstRow = ptT + (size_t)(v * Nk + i) * CINP;

    {
        float gx = proj[n * 2 + 0], gy = proj[n * 2 + 1];
        float ix = fminf(fmaxf(((gx + 1.0f) * (float)WWW - 1.0f) * 0.5f, 0.0f), (float)(WWW - 1));
        float iy = fminf(fmaxf(((gy + 1.0f) * (float)HH - 1.0f) * 0.5f, 0.0f), (float)(HH - 1));
        float x0f = floorf(ix), y0f = floorf(iy);
        float wx = ix - x0f, wy = iy - y0f;
        int x0 = (int)x0f, y0 = (int)y0f;
        int x1 = min(x0 + 1, WWW - 1), y1 = min(y0 + 1, HH - 1);
        const unsigned short* base = imgT + (size_t)v * HH * WWW * C2C;
        us4 a = *((const us4*)(base + ((size_t)(y0 * WWW + x0)) * C2C) + l);
        us4 b = *((const us4*)(base + ((size_t)(y0 * WWW + x1)) * C2C) + l);
        us4 c = *((const us4*)(base + ((size_t)(y1 * WWW + x0)) * C2C) + l);
        us4 d = *((const us4*)(base + ((size_t)(y1 * WWW + x1)) * C2C) + l);
        float w00 = (1.0f - wy) * (1.0f - wx), w01 = (1.0f - wy) * wx;
        float w10 = wy * (1.0f - wx), w11 = wy * wx;
        us4 rv;
#pragma unroll
        for (int r = 0; r < 4; r++) {
            float f = b2f(a[r]) * w00 + b2f(b[r]) * w01 + b2f(c[r]) * w10 + b2f(d[r]) * w11;
            rv[r] = f2b(f);
        }
        *(us4*)(dstRow + l * 4) = rv;
    }
    {
        float gx = pts[n * 3 + 0] * 2.0f, gy = pts[n * 3 + 1] * 2.0f, gz = pts[n * 3 + 2] * 2.0f;
        float ix = fminf(fmaxf(((gx + 1.0f) * (float)DDD - 1.0f) * 0.5f, 0.0f), (float)(DDD - 1));
        float iy = fminf(fmaxf(((gy + 1.0f) * (float)DDD - 1.0f) * 0.5f, 0.0f), (float)(DDD - 1));
        float iz = fminf(fmaxf(((gz + 1.0f) * (float)DDD - 1.0f) * 0.5f, 0.0f), (float)(DDD - 1));
        float x0f = floorf(ix), y0f = floorf(iy), z0f = floorf(iz);
        float wx = ix - x0f, wy = iy - y0f, wz = iz - z0f;
        int x0 = (int)x0f, y0 = (int)y0f, z0 = (int)z0f;
        int x1 = min(x0 + 1, DDD - 1), y1 = min(y0 + 1, DDD - 1), z1 = min(z0 + 1, DDD - 1);
        int c = l & 31, zs = l >> 5;
        int zi = zs ? z1 : z0;
        float wzs = zs ? wz : (1.0f - wz);
        const unsigned short* base = volT + (size_t)v * 32768 * C3C;
        float f00 = b2f(base[((size_t)((zi * 32 + y0) * 32 + x0)) * C3C + c]);
        float f01 = b2f(base[((size_t)((zi * 32 + y0) * 32 + x1)) * C3C + c]);
        float f10 = b2f(base[((size_t)((zi * 32 + y1) * 32 + x0)) * C3C + c]);
        float f11 = b2f(base[((size_t)((zi * 32 + y1) * 32 + x1)) * C3C + c]);
        float r = (f00 * (1.0f - wy) * (1.0f - wx) + f01 * (1.0f - wy) * wx +
                   f10 * wy * (1.0f - wx) + f11 * wy * wx) * wzs;
        float other = __shfl_xor(r, 32);
        r += other;
        if (zs == 0) dstRow[C2C + c] = f2b(r);
    }
    if (l < 8) *(us4*)(dstRow + CINC + l * 4) = (us4){0, 0, 0, 0};
}

__global__ __launch_bounds__(256) void k_sampleL0(const float* p, const float* pr, const unsigned short* im,
                                                  const unsigned short* vo, unsigned short* pt, int n0, int Nk) {
    sample_body(p, pr, im, vo, pt, n0, Nk);
}
__global__ __launch_bounds__(256) void k_sampleL1(const float* p, const float* pr, const unsigned short* im,
                                                  const unsigned short* vo, unsigned short* pt, int n0, int Nk) {
    sample_body(p, pr, im, vo, pt, n0, Nk);
}

// ---------------- g3 + fused W4 dot: 128x128, triple-buffered, no o3 materialization ----------------
template <int K2>
__device__ __forceinline__ void g3dot_body(const unsigned short* __restrict__ A,
                                           const unsigned short* __restrict__ B1,
                                           const unsigned short* __restrict__ B2,
                                           const float* __restrict__ bias,
                                           const float* __restrict__ W4v,
                                           float* __restrict__ dout) {
    constexpr int K1 = CINP;
    constexpr int K = K1 + K2;
    constexpr int nt1 = K1 / 32;
    constexpr int nt = K / 32;
    __shared__ unsigned short Ash[3][128 * 32];
    __shared__ unsigned short Bsh[3][128 * 32];
    __shared__ float ds[128];
    int tid = threadIdx.x;
    int w = tid >> 6, l = tid & 63;
    int la = l & 15, lg = l >> 4;
    int wm = w & 1, wn = w >> 1;
    int nBlk = blockIdx.x * 128;
    int sRow = l >> 2, sCol = (l & 3) * 8;
    int r0 = w * 32 + sRow, r1 = r0 + 16;

    const unsigned short* Ag = A;
    const unsigned short* B1g = B1 + (size_t)nBlk * K1;
    const unsigned short* B2g = B2 + (size_t)nBlk * K2;

    fx4 acc[4][4];
#pragma unroll
    for (int mi = 0; mi < 4; mi++)
#pragma unroll
        for (int ni = 0; ni < 4; ni++) acc[mi][ni] = (fx4){0.f, 0.f, 0.f, 0.f};

    auto stage = [&](int t, int b) {
        const unsigned short* as = Ag + t * 32 + sCol;
        gl2lds16(as + (size_t)r0 * K, &Ash[b][r0 * 32 + sCol]);
        gl2lds16(as + (size_t)r1 * K, &Ash[b][r1 * 32 + sCol]);
        const unsigned short* bs;
        size_t ldb;
        if (t < nt1) { bs = B1g + t * 32 + sCol; ldb = (size_t)K1; }
        else         { bs = B2g + (t - nt1) * 32 + sCol; ldb = (size_t)K2; }
        gl2lds16(bs + (size_t)r0 * ldb, &Bsh[b][r0 * 32 + sCol]);
        gl2lds16(bs + (size_t)r1 * ldb, &Bsh[b][r1 * 32 + sCol]);
    };

    stage(0, 0);
    if (nt > 1) stage(1, 1);
    asm volatile("s_waitcnt vmcnt(4)" ::: "memory");
    __builtin_amdgcn_s_barrier();
    int cur = 0, nxt2 = 2;
    for (int t = 0; t < nt; t++) {
        if (t + 2 < nt) stage(t + 2, nxt2);
        bh8 af[4], bfv[4];
#pragma unroll
        for (int mi = 0; mi < 4; mi++) af[mi] = *(const bh8*)&Ash[cur][(wm * 64 + mi * 16 + la) * 32 + lg * 8];
#pragma unroll
        for (int ni = 0; ni < 4; ni++) bfv[ni] = *(const bh8*)&Bsh[cur][(wn * 64 + ni * 16 + la) * 32 + lg * 8];
#pragma unroll
        for (int mi = 0; mi < 4; mi++)
#pragma unroll
            for (int ni = 0; ni < 4; ni++)
                acc[mi][ni] = __builtin_amdgcn_mfma_f32_16x16x32_bf16(af[mi], bfv[ni], acc[mi][ni], 0, 0, 0);
        asm volatile("s_waitcnt lgkmcnt(0)" ::: "memory");
        if (t + 2 < nt)      asm volatile("s_waitcnt vmcnt(4)" ::: "memory");
        else if (t + 1 < nt) asm volatile("s_waitcnt vmcnt(0)" ::: "memory");
        __builtin_amdgcn_s_barrier();
        cur = (cur == 2) ? 0 : cur + 1;
        nxt2 = (nxt2 == 2) ? 0 : nxt2 + 1;
    }

    if (tid < 128) ds[tid] = 0.0f;
    __syncthreads();
#pragma unroll
    for (int ni = 0; ni < 4; ni++) {
        float part = 0.0f;
#pragma unroll
        for (int mi = 0; mi < 4; mi++) {
            int m0 = wm * 64 + mi * 16 + lg * 4;
            fx4 bb = *(const fx4*)(bias + m0);
#pragma unroll
            for (int r = 0; r < 4; r++) {
                float x = acc[mi][ni][r] + bb[r];
                x = (x >= 0.0f) ? x : 0.2f * x;
                part += W4v[m0 + r] * x;
            }
        }
        part += __shfl_xor(part, 16);
        part += __shfl_xor(part, 32);
        if (lg == 0) atomicAdd(&ds[wn * 64 + ni * 16 + la], part);
    }
    __syncthreads();
    if (tid < 128) dout[nBlk + tid] = ds[tid];
}

__global__ __launch_bounds__(256) void k_g3L0(const unsigned short* A, const unsigned short* B1, const unsigned short* B2,
                                              const float* b, const float* W4, float* dout) { g3dot_body<256>(A, B1, B2, b, W4, dout); }
__global__ __launch_bounds__(256) void k_g3L1(const unsigned short* A, const unsigned short* B1, const unsigned short* B2,
                                              const float* b, const float* W4, float* dout) { g3dot_body<256>(A, B1, B2, b, W4, dout); }

// ---------------- 256x256 4-phase GEMM, counted vmcnt, L2-paired blocks (double-buffered) — for g1 ----------------
template <int KP, int K2, int M, int MB>
__device__ __forceinline__ void g1t_body(const unsigned short* __restrict__ A,
                                         const unsigned short* __restrict__ B1,
                                         const unsigned short* __restrict__ B2,
                                         const float* __restrict__ bias,
                                         unsigned short* __restrict__ C) {
    constexpr int nt = KP >> 6;
    __shared__ unsigned short As[2][256 * 64];
    __shared__ unsigned short Bs[2][256 * 64];
    int tid = threadIdx.x;
    int w = tid >> 6, l = tid & 63;
    int la = l & 15, lg = l >> 4;
    int wm = w >> 2, wn = w & 3;
    int mIdx, nIdx;
    pair_decode<MB>(blockIdx.x, mIdx, nIdx);
    int mBlk = mIdx * 256;
    int nBlk = nIdx * 256;

    const unsigned short* Ag = A + (size_t)mBlk * KP;

    fx4 acc[8][4];
#pragma unroll
    for (int mi = 0; mi < 8; mi++)
#pragma unroll
        for (int ni = 0; ni < 4; ni++) acc[mi][ni] = (fx4){0.f, 0.f, 0.f, 0.f};

    auto stageB = [&](int t, int nxt) {
        const unsigned short* bsrc;
        size_t ldb;
        int kc;
        if (t < 5) { bsrc = B1; ldb = CINP; kc = t * 64; }
        else       { bsrc = B2; ldb = (size_t)K2; kc = (t - 5) * 64; }
        bsrc += (size_t)nBlk * ldb + kc;
#pragma unroll
        for (int h = 0; h < 2; h++)
#pragma unroll
            for (int j = 0; j < 2; j++) {
                int idx = j * 512 + tid;
                int r = (h << 7) + (idx >> 3);
                int c = (idx & 7) ^ (r & 7);
                gl2lds16(bsrc + (size_t)r * ldb + c * 8, &Bs[nxt][(h << 13) + idx * 8]);
            }
    };
    auto stageA1 = [&](int t, int nxt) {
        const unsigned short* asrc = Ag + t * 64;
#pragma unroll
        for (int h = 0; h < 2; h++) {
            int idx = tid;
            int r = (h << 7) + (idx >> 3);
            int c = (idx & 7) ^ (r & 7);
            gl2lds16(asrc + (size_t)r * KP + c * 8, &As[nxt][(h << 13) + idx * 8]);
        }
    };
    auto stageA2 = [&](int t, int nxt) {
        const unsigned short* asrc = Ag + t * 64;
#pragma unroll
        for (int h = 0; h < 2; h++) {
            int idx = 512 + tid;
            int r = (h << 7) + (idx >> 3);
            int c = (idx & 7) ^ (r & 7);
            gl2lds16(asrc + (size_t)r * KP + c * 8, &As[nxt][(h << 13) + idx * 8]);
        }
    };

    stageB(0, 0);
    stageA1(0, 0);
    stageA2(0, 0);
    asm volatile("s_waitcnt vmcnt(0)" ::: "memory");
    __builtin_amdgcn_s_barrier();

    for (int t = 0; t < nt; t++) {
        int cur = t & 1;
        const unsigned short* Ab = &As[cur][0];
        const unsigned short* Bb = &Bs[cur][0];
        bh8 afr[4][2];
#pragma unroll
        for (int p = 0; p < 4; p++) {
            int qm = p >> 1, qn = p & 1;
            if (qn == 0) {
#pragma unroll
                for (int m2 = 0; m2 < 4; m2++)
#pragma unroll
                    for (int s = 0; s < 2; s++) {
                        int row = wm * 128 + (qm * 4 + m2) * 16 + la;
                        int c = (s * 4 + lg) ^ (row & 7);
                        afr[m2][s] = *(const bh8*)&Ab[row * 64 + c * 8];
                    }
            }
            bh8 bfr[2][2];
#pragma unroll
            for (int n2 = 0; n2 < 2; n2++)
#pragma unroll
                for (int s = 0; s < 2; s++) {
                    int row = wn * 64 + (qn * 2 + n2) * 16 + la;
                    int c = (s * 4 + lg) ^ (row & 7);
                    bfr[n2][s] = *(const bh8*)&Bb[row * 64 + c * 8];
                }
            if (p == 0 && t + 1 < nt) stageB(t + 1, cur ^ 1);
            if (p == 1 && t + 1 < nt) stageA1(t + 1, cur ^ 1);
            if (p == 2 && t + 1 < nt) stageA2(t + 1, cur ^ 1);
            __builtin_amdgcn_s_barrier();
            __builtin_amdgcn_s_setprio(1);
#pragma unroll
            for (int m2 = 0; m2 < 4; m2++)
#pragma unroll
                for (int n2 = 0; n2 < 2; n2++)
#pragma unroll
                    for (int s = 0; s < 2; s++)
                        acc[qm * 4 + m2][qn * 2 + n2] = __builtin_amdgcn_mfma_f32_16x16x32_bf16(
                            afr[m2][s], bfr[n2][s], acc[qm * 4 + m2][qn * 2 + n2], 0, 0, 0);
            __builtin_amdgcn_s_setprio(0);
            if (p == 1) {
                if (t + 1 < nt) asm volatile("s_waitcnt vmcnt(6)" ::: "memory");
                else            asm volatile("s_waitcnt vmcnt(0)" ::: "memory");
            }
            if (p == 3) {
                asm volatile("s_waitcnt lgkmcnt(0)" ::: "memory");
                if (t + 1 < nt) asm volatile("s_waitcnt vmcnt(2)" ::: "memory");
            }
            __builtin_amdgcn_s_barrier();
        }
    }

#pragma unroll
    for (int mi = 0; mi < 8; mi++) {
        int m0 = mBlk + wm * 128 + mi * 16 + lg * 4;
        fx4 bb = *(const fx4*)(bias + m0);
#pragma unroll
        for (int ni = 0; ni < 4; ni++) {
            int n = nBlk + wn * 64 + ni * 16 + la;
            us4 rv;
#pragma unroll
            for (int r = 0; r < 4; r++) {
                float x = acc[mi][ni][r] + bb[r];
                x = (x >= 0.0f) ? x : 0.2f * x;
                rv[r] = f2b(x);
            }
            *(us4*)(C + (size_t)n * M + m0) = rv;
        }
    }
}

// ---------------- 256x256 SINGLE-buffer 2-barrier GEMM (64 KB LDS -> 2 blocks/CU) — for g0/g2 ----------------
template <int KP, int K2, int M, int MB>
__device__ __forceinline__ void g2sb_body(const unsigned short* __restrict__ A,
                                          const unsigned short* __restrict__ B1,
                                          const unsigned short* __restrict__ B2,
                                          const float* __restrict__ bias,
                                          unsigned short* __restrict__ C) {
    constexpr int nt = KP >> 6;
    __shared__ unsigned short As[256 * 64];
    __shared__ unsigned short Bs[256 * 64];
    int tid = threadIdx.x;
    int w = tid >> 6, l = tid & 63;
    int la = l & 15, lg = l >> 4;
    int wm = w >> 2, wn = w & 3;
    int mIdx, nIdx;
    pair_decode<MB>(blockIdx.x, mIdx, nIdx);
    int mBlk = mIdx * 256;
    int nBlk = nIdx * 256;

    const unsigned short* Ag = A + (size_t)mBlk * KP;

    fx4 acc[8][4];
#pragma unroll
    for (int mi = 0; mi < 8; mi++)
#pragma unroll
        for (int ni = 0; ni < 4; ni++) acc[mi][ni] = (fx4){0.f, 0.f, 0.f, 0.f};

    auto stage = [&](int t) {
        const unsigned short* bsrc;
        size_t ldb;
        int kc;
        if (t < 5) { bsrc = B1; ldb = CINP; kc = t * 64; }
        else       { bsrc = B2; ldb = (size_t)K2; kc = (t - 5) * 64; }
        bsrc += (size_t)nBlk * ldb + kc;
        const unsigned short* asrc = Ag + t * 64;
#pragma unroll
        for (int h = 0; h < 2; h++)
#pragma unroll
            for (int j = 0; j < 2; j++) {
                int idx = j * 512 + tid;
                int r = (h << 7) + (idx >> 3);
                int c = (idx & 7) ^ (r & 7);
                gl2lds16(asrc + (size_t)r * KP + c * 8, &As[(h << 13) + idx * 8]);
                gl2lds16(bsrc + (size_t)r * ldb + c * 8, &Bs[(h << 13) + idx * 8]);
            }
    };

    for (int t = 0; t < nt; t++) {
        stage(t);
        asm volatile("s_waitcnt vmcnt(0)" ::: "memory");
        __builtin_amdgcn_s_barrier();
        bh8 afr[4][2];
#pragma unroll
        for (int p = 0; p < 4; p++) {
            int qm = p >> 1, qn = p & 1;
            if (qn == 0) {
#pragma unroll
                for (int m2 = 0; m2 < 4; m2++)
#pragma unroll
                    for (int s = 0; s < 2; s++) {
                        int row = wm * 128 + (qm * 4 + m2) * 16 + la;
                        int c = (s * 4 + lg) ^ (row & 7);
                        afr[m2][s] = *(const bh8*)&As[row * 64 + c * 8];
                    }
            }
            bh8 bfr[2][2];
#pragma unroll
            for (int n2 = 0; n2 < 2; n2++)
#pragma unroll
                for (int s = 0; s < 2; s++) {
                    int row = wn * 64 + (qn * 2 + n2) * 16 + la;
                    int c = (s * 4 + lg) ^ (row & 7);
                    bfr[n2][s] = *(const bh8*)&Bs[row * 64 + c * 8];
                }
            __builtin_amdgcn_s_setprio(1);
#pragma unroll
            for (int m2 = 0; m2 < 4; m2++)
#pragma unroll
                for (int n2 = 0; n2 < 2; n2++)
#pragma unroll
                    for (int s = 0; s < 2; s++)
                        acc[qm * 4 + m2][qn * 2 + n2] = __builtin_amdgcn_mfma_f32_16x16x32_bf16(
                            afr[m2][s], bfr[n2][s], acc[qm * 4 + m2][qn * 2 + n2], 0, 0, 0);
            __builtin_amdgcn_s_setprio(0);
        }
        asm volatile("s_waitcnt lgkmcnt(0)" ::: "memory");
        __builtin_amdgcn_s_barrier();
    }

#pragma unroll
    for (int mi = 0; mi < 8; mi++) {
        int m0 = mBlk + wm * 128 + mi * 16 + lg * 4;
        fx4 bb = *(const fx4*)(bias + m0);
#pragma unroll
        for (int ni = 0; ni < 4; ni++) {
            int n = nBlk + wn * 64 + ni * 16 + la;
            us4 rv;
#pragma unroll
            for (int r = 0; r < 4; r++) {
                float x = acc[mi][ni][r] + bb[r];
                x = (x >= 0.0f) ? x : 0.2f * x;
                rv[r] = f2b(x);
            }
            *(us4*)(C + (size_t)n * M + m0) = rv;
        }
    }
}

__global__ __launch_bounds__(512) void k_g0L0(const unsigned short* A, const unsigned short* B1,
                                              const float* b, unsigned short* C) { g2sb_body<320, 0, 1024, 4>(A, B1, nullptr, b, C); }
__global__ __launch_bounds__(512) void k_g0L1(const unsigned short* A, const unsigned short* B1,
                                              const float* b, unsigned short* C) { g2sb_body<320, 0, 1024, 4>(A, B1, nullptr, b, C); }
__global__ __launch_bounds__(512) void k_g1L0(const unsigned short* A, const unsigned short* B1, const unsigned short* B2,
                                              const float* b, unsigned short* C) { g1t_body<1344, 1024, 512, 2>(A, B1, B2, b, C); }
__global__ __launch_bounds__(512) void k_g1L1(const unsigned short* A, const unsigned short* B1, const unsigned short* B2,
                                              const float* b, unsigned short* C) { g1t_body<1344, 1024, 512, 2>(A, B1, B2, b, C); }
__global__ __launch_bounds__(512) void k_g2L0(const unsigned short* A, const unsigned short* B1, const unsigned short* B2,
                                              const float* b, unsigned short* C) { g2sb_body<832, 512, 256, 1>(A, B1, B2, b, C); }
__global__ __launch_bounds__(512) void k_g2L1(const unsigned short* A, const unsigned short* B1, const unsigned short* B2,
                                              const float* b, unsigned short* C) { g2sb_body<832, 512, 256, 1>(A, B1, B2, b, C); }

// ---------------- finish: mean of per-view dots, sigmoid — both levels, one launch ----------------
__global__ __launch_bounds__(256) void k_fin2(const float* __restrict__ d0v, const float* __restrict__ d1v,
                                              const float* __restrict__ b4, const int* __restrict__ mn_p,
                                              float* __restrict__ out, int n0, int Nk) {
    int i = blockIdx.x * 256 + threadIdx.x;
    int lvl = blockIdx.y;
    if (i >= Nk) return;
    const float* d = lvl ? d1v : d0v;
    int mn = *mn_p;
    if (mn > NV) mn = NV;
    if (mn < 1) mn = 1;
    float s = 0.0f;
    for (int v = 0; v < mn; v++) s += d[(size_t)v * Nk + i];
    s = s / (float)mn + b4[0];
    out[(size_t)lvl * NPTS + n0 + i] = 1.0f / (1.0f + expf(-s));
}

extern "C" void kernel_launch(void* const* d_in, const int* in_sizes, int n_in,
                              void* d_out, int out_size, void* d_ws, size_t ws_size,
                              hipStream_t stream) {
    const float* pts = (const float*)d_in[0];
    const float* proj = (const float*)d_in[1];
    const float* img[2] = {(const float*)d_in[2], (const float*)d_in[3]};
    const float* vol[2] = {(const float*)d_in[4], (const float*)d_in[5]};
    const float* Wf[4] = {(const float*)d_in[6], (const float*)d_in[8], (const float*)d_in[10], (const float*)d_in[12]};
    const float* bf[4] = {(const float*)d_in[7], (const float*)d_in[9], (const float*)d_in[11], (const float*)d_in[13]};
    const float* W4 = (const float*)d_in[14];
    const float* b4 = (const float*)d_in[15];
    const int* mn = (const int*)d_in[16];
    float* out = (float*)d_out;

    const int Kp[4] = {320, 1344, 832, 576};
    const int Msz[4] = {1024, 512, 256, 128};

    char* ws = (char*)d_ws;
    size_t off = 0;
    auto alloc = [&](size_t bytes) -> char* {
        char* p = ws + off;
        off = (off + bytes + 255) & ~(size_t)255;
        return p;
    };

    const size_t imgStride = (size_t)NV * HH * WWW * C2C;
    const size_t volStride = (size_t)NV * 32768 * C3C;

    unsigned short* Wb[4];
    for (int i = 0; i < 4; i++) Wb[i] = (unsigned short*)alloc((size_t)Msz[i] * Kp[i] * 2);
    unsigned short* imgT = (unsigned short*)alloc(2 * imgStride * 2);
    unsigned short* volT = (unsigned short*)alloc(2 * volStride * 2);
    size_t fixed = off;

    const size_t perPt = (size_t)NV * (2 * (CINP + 1024 + 512) + 8);
    int Nk = NPTS;
    if (fixed + (size_t)Nk * perPt + 4096 > ws_size) {
        size_t avail = (ws_size > fixed + 4096) ? (ws_size - fixed - 4096) : 0;
        long nk = (long)(avail / perPt);
        nk = (nk / 2048) * 2048;
        if (nk < 2048) nk = 2048;
        if (nk > NPTS) nk = NPTS;
        Nk = (int)nk;
    }
    unsigned short* ptT = (unsigned short*)alloc((size_t)NV * Nk * CINP * 2);
    unsigned short* o0 = (unsigned short*)alloc((size_t)NV * Nk * 1024 * 2);
    unsigned short* o1 = (unsigned short*)alloc((size_t)NV * Nk * 512 * 2);
    unsigned short* o2 = o0;  // alias: o0 dead once g2 runs
    float* dsum0 = (float*)alloc((size_t)NV * Nk * 4);
    float* dsum1 = (float*)alloc((size_t)NV * Nk * 4);

    k_prep<<<12000, 256, 0, stream>>>(Wf[0], Wf[1], Wf[2], Wf[3], Wb[0], Wb[1], Wb[2], Wb[3],
                                      img[0], img[1], imgT, imgStride, vol[0], vol[1], volT, volStride);

    for (int n0 = 0; n0 < NPTS; n0 += Nk) {
        int nk = NPTS - n0 < Nk ? NPTS - n0 : Nk;
        int NC = NV * nk;
        int nP256 = NC / 256;
        int nP128 = NC / 128;
        // level 0
        k_sampleL0<<<dim3(nk / 4, NV), 256, 0, stream>>>(pts, proj, imgT, volT, ptT, n0, nk);
        k_g0L0<<<4 * nP256, 512, 0, stream>>>(Wb[0], ptT, bf[0], o0);
        k_g1L0<<<2 * nP256, 512, 0, stream>>>(Wb[1], ptT, o0, bf[1], o1);
        k_g2L0<<<nP256, 512, 0, stream>>>(Wb[2], ptT, o1, bf[2], o2);
        k_g3L0<<<nP128, 256, 0, stream>>>(Wb[3], ptT, o2, bf[3], W4, dsum0);
        // level 1
        k_sampleL1<<<dim3(nk / 4, NV), 256, 0, stream>>>(pts, proj, imgT + imgStride, volT + volStride, ptT, n0, nk);
        k_g0L1<<<4 * nP256, 512, 0, stream>>>(Wb[0], ptT, bf[0], o0);
        k_g1L1<<<2 * nP256, 512, 0, stream>>>(Wb[1], ptT, o0, bf[1], o1);
        k_g2L1<<<nP256, 512, 0, stream>>>(Wb[2], ptT, o1, bf[2], o2);
        k_g3L1<<<nP128, 256, 0, stream>>>(Wb[3], ptT, o2, bf[3], W4, dsum1);
        // both levels
        k_fin2<<<dim3((nk + 255) / 256, 2), 256, 0, stream>>>(dsum0, dsum1, b4, mn, out, n0, nk);
    }
}

// Round 16
// 1002.460 us; speedup vs baseline: 1.0328x; 1.0328x over previous
//
#include <hip/hip_runtime.h>
#include <hip/hip_bf16.h>

#define NV 3
#define NPTS 32768
#define C2C 256
#define C3C 32
#define CINC 288
#define CINP 320
#define HH 128
#define WWW 128
#define DDD 32

typedef short bh8 __attribute__((ext_vector_type(8)));
typedef float fx4 __attribute__((ext_vector_type(4)));
typedef unsigned short us4 __attribute__((ext_vector_type(4)));

__device__ __forceinline__ float b2f(unsigned short u) {
    unsigned int x = ((unsigned int)u) << 16;
    return __uint_as_float(x);
}
__device__ __forceinline__ unsigned short f2b(float f) {
    unsigned int x = __float_as_uint(f);
    unsigned int r = (x + 0x7FFFu + ((x >> 16) & 1u)) >> 16;
    return (unsigned short)r;
}

__device__ __forceinline__ void gl2lds16(const unsigned short* g, unsigned short* l) {
    __builtin_amdgcn_global_load_lds(
        (const __attribute__((address_space(1))) unsigned int*)g,
        (__attribute__((address_space(3))) unsigned int*)l, 16, 0, 0);
}

// L2-pairing block decode (requires n-panels % 8 == 0)
template <int MB>
__device__ __forceinline__ void pair_decode(int b, int& mIdx, int& nIdx) {
    constexpr int L = (MB == 1) ? 0 : (MB == 2) ? 1 : 2;
    nIdx = ((b >> (3 + L)) << 3) | (b & 7);
    mIdx = (b >> 3) & (MB - 1);
}

// ---------------- merged prep: weight pad-cast + img transpose + vol transpose ----------------
__global__ __launch_bounds__(256) void k_prep(
    const float* __restrict__ s0, const float* __restrict__ s1,
    const float* __restrict__ s2, const float* __restrict__ s3,
    unsigned short* __restrict__ d0, unsigned short* __restrict__ d1,
    unsigned short* __restrict__ d2, unsigned short* __restrict__ d3,
    const float* __restrict__ img0, const float* __restrict__ img1,
    unsigned short* __restrict__ imgT, size_t imgStride,
    const float* __restrict__ vol0, const float* __restrict__ vol1,
    unsigned short* __restrict__ volT, size_t volStride) {
    __shared__ float smem[32 * 257];
    int b = blockIdx.x;
    if (b < 5088) {
        int base, M, Kp;
        const float* src;
        unsigned short* dst;
        if (b < 1280)      { base = 0;    M = 1024; Kp = 320;  src = s0; dst = d0; }
        else if (b < 3968) { base = 1280; M = 512;  Kp = 1344; src = s1; dst = d1; }
        else if (b < 4800) { base = 3968; M = 256;  Kp = 832;  src = s2; dst = d2; }
        else               { base = 4800; M = 128;  Kp = 576;  src = s3; dst = d3; }
        int idx = (b - base) * 256 + threadIdx.x;
        if (idx >= M * Kp) return;
        int m = idx / Kp, k = idx - m * Kp;
        int Ksrc = Kp - 32;
        float v;
        if (k < CINC) v = src[(size_t)m * Ksrc + k];
        else if (k < CINP) v = 0.0f;
        else v = src[(size_t)m * Ksrc + (k - 32)];
        dst[idx] = f2b(v);
    } else if (b < 11232) {
        int id = b - 5088;
        int bx = id % 384, by = (id / 384) & 1, bz = id / 768;
        int lvl = bz >> 2, cb = bz & 3;
        const float* in = lvl ? img1 : img0;
        int v = bx >> 7, y = bx & 127;
        int x0 = by << 6, c0 = cb << 6;
        float (*t)[65] = (float(*)[65])smem;
        int tx = threadIdx.x & 63, tg = threadIdx.x >> 6;
        const float* src = in + (((size_t)(v * C2C + c0) * HH + y) * WWW + x0);
#pragma unroll
        for (int i = 0; i < 16; i++) {
            int cl = tg * 16 + i;
            t[cl][tx] = src[(size_t)cl * (HH * WWW) + tx];
        }
        __syncthreads();
        unsigned short* dst = imgT + lvl * imgStride + ((size_t)(v * HH + y) * WWW + x0) * C2C + c0;
#pragma unroll
        for (int i = 0; i < 16; i++) {
            int xl = tg * 16 + i;
            dst[(size_t)xl * C2C + tx] = f2b(t[tx][xl]);
        }
    } else {
        int id = b - 11232;
        int v = id % 3, sy = (id / 3) & 127, lvl = id / 384;
        const float* in = lvl ? vol1 : vol0;
        int s0i = sy << 8;
        float (*t)[257] = (float(*)[257])smem;
        int tid = threadIdx.x;
        const float* src = in + (size_t)v * C3C * 32768 + s0i;
#pragma unroll
        for (int c = 0; c < 32; c++) t[c][tid] = src[(size_t)c * 32768 + tid];
        __syncthreads();
        unsigned short* dst = volT + lvl * volStride + ((size_t)v * 32768 + s0i) * C3C;
        int c = tid & 31, sb = tid >> 5;
#pragma unroll
        for (int j = 0; j < 32; j++) {
            int sl = j * 8 + sb;
            dst[(size_t)sl * C3C + c] = f2b(t[c][sl]);
        }
    }
}

// ---------------- sampler body: wave per (point,view) ----------------
__device__ __forceinline__ void sample_body(const float* __restrict__ pts, const float* __restrict__ proj,
                         const unsigned short* __restrict__ imgT, const unsigned short* __restrict__ volT,
                         unsigned short* __restrict__ ptT, int n0, int Nk) {
    int w = threadIdx.x >> 6, l = threadIdx.x & 63;
    int i = blockIdx.x * 4 + w;
    int v = blockIdx.y;
    int n = n0 + i;
    unsigned short* dstRow = ptT + (size_t)(v * Nk + i) * CINP;

    {
        float gx = proj[n * 2 + 0], gy = proj[n * 2 + 1];
        float ix = fminf(fmaxf(((gx + 1.0f) * (float)WWW - 1.0f) * 0.5f, 0.0f), (float)(WWW - 1));
        float iy = fminf(fmaxf(((gy + 1.0f) * (float)HH - 1.0f) * 0.5f, 0.0f), (float)(HH - 1));
        float x0f = floorf(ix), y0f = floorf(iy);
        float wx = ix - x0f, wy = iy - y0f;
        int x0 = (int)x0f, y0 = (int)y0f;
        int x1 = min(x0 + 1, WWW - 1), y1 = min(y0 + 1, HH - 1);
        const unsigned short* base = imgT + (size_t)v * HH * WWW * C2C;
        us4 a = *((const us4*)(base + ((size_t)(y0 * WWW + x0)) * C2C) + l);
        us4 b = *((const us4*)(base + ((size_t)(y0 * WWW + x1)) * C2C) + l);
        us4 c = *((const us4*)(base + ((size_t)(y1 * WWW + x0)) * C2C) + l);
        us4 d = *((const us4*)(base + ((size_t)(y1 * WWW + x1)) * C2C) + l);
        float w00 = (1.0f - wy) * (1.0f - wx), w01 = (1.0f - wy) * wx;
        float w10 = wy * (1.0f - wx), w11 = wy * wx;
        us4 rv;
#pragma unroll
        for (int r = 0; r < 4; r++) {
            float f = b2f(a[r]) * w00 + b2f(b[r]) * w01 + b2f(c[r]) * w10 + b2f(d[r]) * w11;
            rv[r] = f2b(f);
        }
        *(us4*)(dstRow + l * 4) = rv;
    }
    {
        float gx = pts[n * 3 + 0] * 2.0f, gy = pts[n * 3 + 1] * 2.0f, gz = pts[n * 3 + 2] * 2.0f;
        float ix = fminf(fmaxf(((gx + 1.0f) * (float)DDD - 1.0f) * 0.5f, 0.0f), (float)(DDD - 1));
        float iy = fminf(fmaxf(((gy + 1.0f) * (float)DDD - 1.0f) * 0.5f, 0.0f), (float)(DDD - 1));
        float iz = fminf(fmaxf(((gz + 1.0f) * (float)DDD - 1.0f) * 0.5f, 0.0f), (float)(DDD - 1));
        float x0f = floorf(ix), y0f = floorf(iy), z0f = floorf(iz);
        float wx = ix - x0f, wy = iy - y0f, wz = iz - z0f;
        int x0 = (int)x0f, y0 = (int)y0f, z0 = (int)z0f;
        int x1 = min(x0 + 1, DDD - 1), y1 = min(y0 + 1, DDD - 1), z1 = min(z0 + 1, DDD - 1);
        int c = l & 31, zs = l >> 5;
        int zi = zs ? z1 : z0;
        float wzs = zs ? wz : (1.0f - wz);
        const unsigned short* base = volT + (size_t)v * 32768 * C3C;
        float f00 = b2f(base[((size_t)((zi * 32 + y0) * 32 + x0)) * C3C + c]);
        float f01 = b2f(base[((size_t)((zi * 32 + y0) * 32 + x1)) * C3C + c]);
        float f10 = b2f(base[((size_t)((zi * 32 + y1) * 32 + x0)) * C3C + c]);
        float f11 = b2f(base[((size_t)((zi * 32 + y1) * 32 + x1)) * C3C + c]);
        float r = (f00 * (1.0f - wy) * (1.0f - wx) + f01 * (1.0f - wy) * wx +
                   f10 * wy * (1.0f - wx) + f11 * wy * wx) * wzs;
        float other = __shfl_xor(r, 32);
        r += other;
        if (zs == 0) dstRow[C2C + c] = f2b(r);
    }
    if (l < 8) *(us4*)(dstRow + CINC + l * 4) = (us4){0, 0, 0, 0};
}

__global__ __launch_bounds__(256) void k_sampleL0(const float* p, const float* pr, const unsigned short* im,
                                                  const unsigned short* vo, unsigned short* pt, int n0, int Nk) {
    sample_body(p, pr, im, vo, pt, n0, Nk);
}
__global__ __launch_bounds__(256) void k_sampleL1(const float* p, const float* pr, const unsigned short* im,
                                                  const unsigned short* vo, unsigned short* pt, int n0, int Nk) {
    sample_body(p, pr, im, vo, pt, n0, Nk);
}

// ---------------- g3 + fused W4 dot: 128x128, triple-buffered, no o3 materialization ----------------
template <int K2>
__device__ __forceinline__ void g3dot_body(const unsigned short* __restrict__ A,
                                           const unsigned short* __restrict__ B1,
                                           const unsigned short* __restrict__ B2,
                                           const float* __restrict__ bias,
                                           const float* __restrict__ W4v,
                                           float* __restrict__ dout) {
    constexpr int K1 = CINP;
    constexpr int K = K1 + K2;
    constexpr int nt1 = K1 / 32;
    constexpr int nt = K / 32;
    __shared__ unsigned short Ash[3][128 * 32];
    __shared__ unsigned short Bsh[3][128 * 32];
    __shared__ float ds[128];
    int tid = threadIdx.x;
    int w = tid >> 6, l = tid & 63;
    int la = l & 15, lg = l >> 4;
    int wm = w & 1, wn = w >> 1;
    int nBlk = blockIdx.x * 128;
    int sRow = l >> 2, sCol = (l & 3) * 8;
    int r0 = w * 32 + sRow, r1 = r0 + 16;

    const unsigned short* Ag = A;
    const unsigned short* B1g = B1 + (size_t)nBlk * K1;
    const unsigned short* B2g = B2 + (size_t)nBlk * K2;

    fx4 acc[4][4];
#pragma unroll
    for (int mi = 0; mi < 4; mi++)
#pragma unroll
        for (int ni = 0; ni < 4; ni++) acc[mi][ni] = (fx4){0.f, 0.f, 0.f, 0.f};

    auto stage = [&](int t, int b) {
        const unsigned short* as = Ag + t * 32 + sCol;
        gl2lds16(as + (size_t)r0 * K, &Ash[b][r0 * 32 + sCol]);
        gl2lds16(as + (size_t)r1 * K, &Ash[b][r1 * 32 + sCol]);
        const unsigned short* bs;
        size_t ldb;
        if (t < nt1) { bs = B1g + t * 32 + sCol; ldb = (size_t)K1; }
        else         { bs = B2g + (t - nt1) * 32 + sCol; ldb = (size_t)K2; }
        gl2lds16(bs + (size_t)r0 * ldb, &Bsh[b][r0 * 32 + sCol]);
        gl2lds16(bs + (size_t)r1 * ldb, &Bsh[b][r1 * 32 + sCol]);
    };

    stage(0, 0);
    if (nt > 1) stage(1, 1);
    asm volatile("s_waitcnt vmcnt(4)" ::: "memory");
    __builtin_amdgcn_s_barrier();
    int cur = 0, nxt2 = 2;
    for (int t = 0; t < nt; t++) {
        if (t + 2 < nt) stage(t + 2, nxt2);
        bh8 af[4], bfv[4];
#pragma unroll
        for (int mi = 0; mi < 4; mi++) af[mi] = *(const bh8*)&Ash[cur][(wm * 64 + mi * 16 + la) * 32 + lg * 8];
#pragma unroll
        for (int ni = 0; ni < 4; ni++) bfv[ni] = *(const bh8*)&Bsh[cur][(wn * 64 + ni * 16 + la) * 32 + lg * 8];
#pragma unroll
        for (int mi = 0; mi < 4; mi++)
#pragma unroll
            for (int ni = 0; ni < 4; ni++)
                acc[mi][ni] = __builtin_amdgcn_mfma_f32_16x16x32_bf16(af[mi], bfv[ni], acc[mi][ni], 0, 0, 0);
        asm volatile("s_waitcnt lgkmcnt(0)" ::: "memory");
        if (t + 2 < nt)      asm volatile("s_waitcnt vmcnt(4)" ::: "memory");
        else if (t + 1 < nt) asm volatile("s_waitcnt vmcnt(0)" ::: "memory");
        __builtin_amdgcn_s_barrier();
        cur = (cur == 2) ? 0 : cur + 1;
        nxt2 = (nxt2 == 2) ? 0 : nxt2 + 1;
    }

    if (tid < 128) ds[tid] = 0.0f;
    __syncthreads();
#pragma unroll
    for (int ni = 0; ni < 4; ni++) {
        float part = 0.0f;
#pragma unroll
        for (int mi = 0; mi < 4; mi++) {
            int m0 = wm * 64 + mi * 16 + lg * 4;
            fx4 bb = *(const fx4*)(bias + m0);
#pragma unroll
            for (int r = 0; r < 4; r++) {
                float x = acc[mi][ni][r] + bb[r];
                x = (x >= 0.0f) ? x : 0.2f * x;
                part += W4v[m0 + r] * x;
            }
        }
        part += __shfl_xor(part, 16);
        part += __shfl_xor(part, 32);
        if (lg == 0) atomicAdd(&ds[wn * 64 + ni * 16 + la], part);
    }
    __syncthreads();
    if (tid < 128) dout[nBlk + tid] = ds[tid];
}

__global__ __launch_bounds__(256) void k_g3L0(const unsigned short* A, const unsigned short* B1, const unsigned short* B2,
                                              const float* b, const float* W4, float* dout) { g3dot_body<256>(A, B1, B2, b, W4, dout); }
__global__ __launch_bounds__(256) void k_g3L1(const unsigned short* A, const unsigned short* B1, const unsigned short* B2,
                                              const float* b, const float* W4, float* dout) { g3dot_body<256>(A, B1, B2, b, W4, dout); }

// ---------------- 256x256 4-phase GEMM, counted vmcnt, L2-paired blocks (double-buffered) — g0/g1 ----------------
template <int KP, int K2, int M, int MB>
__device__ __forceinline__ void g1t_body(const unsigned short* __restrict__ A,
                                         const unsigned short* __restrict__ B1,
                                         const unsigned short* __restrict__ B2,
                                         const float* __restrict__ bias,
                                         unsigned short* __restrict__ C) {
    constexpr int nt = KP >> 6;
    __shared__ unsigned short As[2][256 * 64];
    __shared__ unsigned short Bs[2][256 * 64];
    int tid = threadIdx.x;
    int w = tid >> 6, l = tid & 63;
    int la = l & 15, lg = l >> 4;
    int wm = w >> 2, wn = w & 3;
    int mIdx, nIdx;
    pair_decode<MB>(blockIdx.x, mIdx, nIdx);
    int mBlk = mIdx * 256;
    int nBlk = nIdx * 256;

    const unsigned short* Ag = A + (size_t)mBlk * KP;

    fx4 acc[8][4];
#pragma unroll
    for (int mi = 0; mi < 8; mi++)
#pragma unroll
        for (int ni = 0; ni < 4; ni++) acc[mi][ni] = (fx4){0.f, 0.f, 0.f, 0.f};

    auto stageB = [&](int t, int nxt) {
        const unsigned short* bsrc;
        size_t ldb;
        int kc;
        if (t < 5) { bsrc = B1; ldb = CINP; kc = t * 64; }
        else       { bsrc = B2; ldb = (size_t)K2; kc = (t - 5) * 64; }
        bsrc += (size_t)nBlk * ldb + kc;
#pragma unroll
        for (int h = 0; h < 2; h++)
#pragma unroll
            for (int j = 0; j < 2; j++) {
                int idx = j * 512 + tid;
                int r = (h << 7) + (idx >> 3);
                int c = (idx & 7) ^ (r & 7);
                gl2lds16(bsrc + (size_t)r * ldb + c * 8, &Bs[nxt][(h << 13) + idx * 8]);
            }
    };
    auto stageA1 = [&](int t, int nxt) {
        const unsigned short* asrc = Ag + t * 64;
#pragma unroll
        for (int h = 0; h < 2; h++) {
            int idx = tid;
            int r = (h << 7) + (idx >> 3);
            int c = (idx & 7) ^ (r & 7);
            gl2lds16(asrc + (size_t)r * KP + c * 8, &As[nxt][(h << 13) + idx * 8]);
        }
    };
    auto stageA2 = [&](int t, int nxt) {
        const unsigned short* asrc = Ag + t * 64;
#pragma unroll
        for (int h = 0; h < 2; h++) {
            int idx = 512 + tid;
            int r = (h << 7) + (idx >> 3);
            int c = (idx & 7) ^ (r & 7);
            gl2lds16(asrc + (size_t)r * KP + c * 8, &As[nxt][(h << 13) + idx * 8]);
        }
    };

    stageB(0, 0);
    stageA1(0, 0);
    stageA2(0, 0);
    asm volatile("s_waitcnt vmcnt(0)" ::: "memory");
    __builtin_amdgcn_s_barrier();

    for (int t = 0; t < nt; t++) {
        int cur = t & 1;
        const unsigned short* Ab = &As[cur][0];
        const unsigned short* Bb = &Bs[cur][0];
        bh8 afr[4][2];
#pragma unroll
        for (int p = 0; p < 4; p++) {
            int qm = p >> 1, qn = p & 1;
            if (qn == 0) {
#pragma unroll
                for (int m2 = 0; m2 < 4; m2++)
#pragma unroll
                    for (int s = 0; s < 2; s++) {
                        int row = wm * 128 + (qm * 4 + m2) * 16 + la;
                        int c = (s * 4 + lg) ^ (row & 7);
                        afr[m2][s] = *(const bh8*)&Ab[row * 64 + c * 8];
                    }
            }
            bh8 bfr[2][2];
#pragma unroll
            for (int n2 = 0; n2 < 2; n2++)
#pragma unroll
                for (int s = 0; s < 2; s++) {
                    int row = wn * 64 + (qn * 2 + n2) * 16 + la;
                    int c = (s * 4 + lg) ^ (row & 7);
                    bfr[n2][s] = *(const bh8*)&Bb[row * 64 + c * 8];
                }
            if (p == 0 && t + 1 < nt) stageB(t + 1, cur ^ 1);
            if (p == 1 && t + 1 < nt) stageA1(t + 1, cur ^ 1);
            if (p == 2 && t + 1 < nt) stageA2(t + 1, cur ^ 1);
            __builtin_amdgcn_s_barrier();
            __builtin_amdgcn_s_setprio(1);
#pragma unroll
            for (int m2 = 0; m2 < 4; m2++)
#pragma unroll
                for (int n2 = 0; n2 < 2; n2++)
#pragma unroll
                    for (int s = 0; s < 2; s++)
                        acc[qm * 4 + m2][qn * 2 + n2] = __builtin_amdgcn_mfma_f32_16x16x32_bf16(
                            afr[m2][s], bfr[n2][s], acc[qm * 4 + m2][qn * 2 + n2], 0, 0, 0);
            __builtin_amdgcn_s_setprio(0);
            if (p == 1) {
                if (t + 1 < nt) asm volatile("s_waitcnt vmcnt(6)" ::: "memory");
                else            asm volatile("s_waitcnt vmcnt(0)" ::: "memory");
            }
            if (p == 3) {
                asm volatile("s_waitcnt lgkmcnt(0)" ::: "memory");
                if (t + 1 < nt) asm volatile("s_waitcnt vmcnt(2)" ::: "memory");
            }
            __builtin_amdgcn_s_barrier();
        }
    }

#pragma unroll
    for (int mi = 0; mi < 8; mi++) {
        int m0 = mBlk + wm * 128 + mi * 16 + lg * 4;
        fx4 bb = *(const fx4*)(bias + m0);
#pragma unroll
        for (int ni = 0; ni < 4; ni++) {
            int n = nBlk + wn * 64 + ni * 16 + la;
            us4 rv;
#pragma unroll
            for (int r = 0; r < 4; r++) {
                float x = acc[mi][ni][r] + bb[r];
                x = (x >= 0.0f) ? x : 0.2f * x;
                rv[r] = f2b(x);
            }
            *(us4*)(C + (size_t)n * M + m0) = rv;
        }
    }
}

// ---------------- 256x256 SINGLE-buffer 2-barrier GEMM (64 KB LDS -> 2 blocks/CU) — for g2 ----------------
template <int KP, int K2, int M>
__device__ __forceinline__ void g2sb_body(const unsigned short* __restrict__ A,
                                          const unsigned short* __restrict__ B1,
                                          const unsigned short* __restrict__ B2,
                                          const float* __restrict__ bias,
                                          unsigned short* __restrict__ C) {
    constexpr int nt = KP >> 6;
    __shared__ unsigned short As[256 * 64];
    __shared__ unsigned short Bs[256 * 64];
    int tid = threadIdx.x;
    int w = tid >> 6, l = tid & 63;
    int la = l & 15, lg = l >> 4;
    int wm = w >> 2, wn = w & 3;
    int nBlk = blockIdx.x * 256;

    const unsigned short* Ag = A;

    fx4 acc[8][4];
#pragma unroll
    for (int mi = 0; mi < 8; mi++)
#pragma unroll
        for (int ni = 0; ni < 4; ni++) acc[mi][ni] = (fx4){0.f, 0.f, 0.f, 0.f};

    auto stage = [&](int t) {
        const unsigned short* bsrc;
        size_t ldb;
        int kc;
        if (t < 5) { bsrc = B1; ldb = CINP; kc = t * 64; }
        else       { bsrc = B2; ldb = (size_t)K2; kc = (t - 5) * 64; }
        bsrc += (size_t)nBlk * ldb + kc;
        const unsigned short* asrc = Ag + t * 64;
#pragma unroll
        for (int h = 0; h < 2; h++)
#pragma unroll
            for (int j = 0; j < 2; j++) {
                int idx = j * 512 + tid;
                int r = (h << 7) + (idx >> 3);
                int c = (idx & 7) ^ (r & 7);
                gl2lds16(asrc + (size_t)r * KP + c * 8, &As[(h << 13) + idx * 8]);
                gl2lds16(bsrc + (size_t)r * ldb + c * 8, &Bs[(h << 13) + idx * 8]);
            }
    };

    for (int t = 0; t < nt; t++) {
        stage(t);
        asm volatile("s_waitcnt vmcnt(0)" ::: "memory");
        __builtin_amdgcn_s_barrier();
        bh8 afr[4][2];
#pragma unroll
        for (int p = 0; p < 4; p++) {
            int qm = p >> 1, qn = p & 1;
            if (qn == 0) {
#pragma unroll
                for (int m2 = 0; m2 < 4; m2++)
#pragma unroll
                    for (int s = 0; s < 2; s++) {
                        int row = wm * 128 + (qm * 4 + m2) * 16 + la;
                        int c = (s * 4 + lg) ^ (row & 7);
                        afr[m2][s] = *(const bh8*)&As[row * 64 + c * 8];
                    }
            }
            bh8 bfr[2][2];
#pragma unroll
            for (int n2 = 0; n2 < 2; n2++)
#pragma unroll
                for (int s = 0; s < 2; s++) {
                    int row = wn * 64 + (qn * 2 + n2) * 16 + la;
                    int c = (s * 4 + lg) ^ (row & 7);
                    bfr[n2][s] = *(const bh8*)&Bs[row * 64 + c * 8];
                }
            __builtin_amdgcn_s_setprio(1);
#pragma unroll
            for (int m2 = 0; m2 < 4; m2++)
#pragma unroll
                for (int n2 = 0; n2 < 2; n2++)
#pragma unroll
                    for (int s = 0; s < 2; s++)
                        acc[qm * 4 + m2][qn * 2 + n2] = __builtin_amdgcn_mfma_f32_16x16x32_bf16(
                            afr[m2][s], bfr[n2][s], acc[qm * 4 + m2][qn * 2 + n2], 0, 0, 0);
            __builtin_amdgcn_s_setprio(0);
        }
        asm volatile("s_waitcnt lgkmcnt(0)" ::: "memory");
        __builtin_amdgcn_s_barrier();
    }

#pragma unroll
    for (int mi = 0; mi < 8; mi++) {
        int m0 = wm * 128 + mi * 16 + lg * 4;
        fx4 bb = *(const fx4*)(bias + m0);
#pragma unroll
        for (int ni = 0; ni < 4; ni++) {
            int n = nBlk + wn * 64 + ni * 16 + la;
            us4 rv;
#pragma unroll
            for (int r = 0; r < 4; r++) {
                float x = acc[mi][ni][r] + bb[r];
                x = (x >= 0.0f) ? x : 0.2f * x;
                rv[r] = f2b(x);
            }
            *(us4*)(C + (size_t)n * M + m0) = rv;
        }
    }
}

__global__ __launch_bounds__(512) void k_g0L0(const unsigned short* A, const unsigned short* B1,
                                              const float* b, unsigned short* C) { g1t_body<320, 0, 1024, 4>(A, B1, nullptr, b, C); }
__global__ __launch_bounds__(512) void k_g0L1(const unsigned short* A, const unsigned short* B1,
                                              const float* b, unsigned short* C) { g1t_body<320, 0, 1024, 4>(A, B1, nullptr, b, C); }
__global__ __launch_bounds__(512) void k_g1L0(const unsigned short* A, const unsigned short* B1, const unsigned short* B2,
                                              const float* b, unsigned short* C) { g1t_body<1344, 1024, 512, 2>(A, B1, B2, b, C); }
__global__ __launch_bounds__(512) void k_g1L1(const unsigned short* A, const unsigned short* B1, const unsigned short* B2,
                                              const float* b, unsigned short* C) { g1t_body<1344, 1024, 512, 2>(A, B1, B2, b, C); }
__global__ __launch_bounds__(512) void k_g2L0(const unsigned short* A, const unsigned short* B1, const unsigned short* B2,
                                              const float* b, unsigned short* C) { g2sb_body<832, 512, 256>(A, B1, B2, b, C); }
__global__ __launch_bounds__(512) void k_g2L1(const unsigned short* A, const unsigned short* B1, const unsigned short* B2,
                                              const float* b, unsigned short* C) { g2sb_body<832, 512, 256>(A, B1, B2, b, C); }

// ---------------- finish: mean of per-view dots, sigmoid — both levels, one launch ----------------
__global__ __launch_bounds__(256) void k_fin2(const float* __restrict__ d0v, const float* __restrict__ d1v,
                                              const float* __restrict__ b4, const int* __restrict__ mn_p,
                                              float* __restrict__ out, int n0, int Nk) {
    int i = blockIdx.x * 256 + threadIdx.x;
    int lvl = blockIdx.y;
    if (i >= Nk) return;
    const float* d = lvl ? d1v : d0v;
    int mn = *mn_p;
    if (mn > NV) mn = NV;
    if (mn < 1) mn = 1;
    float s = 0.0f;
    for (int v = 0; v < mn; v++) s += d[(size_t)v * Nk + i];
    s = s / (float)mn + b4[0];
    out[(size_t)lvl * NPTS + n0 + i] = 1.0f / (1.0f + expf(-s));
}

extern "C" void kernel_launch(void* const* d_in, const int* in_sizes, int n_in,
                              void* d_out, int out_size, void* d_ws, size_t ws_size,
                              hipStream_t stream) {
    const float* pts = (const float*)d_in[0];
    const float* proj = (const float*)d_in[1];
    const float* img[2] = {(const float*)d_in[2], (const float*)d_in[3]};
    const float* vol[2] = {(const float*)d_in[4], (const float*)d_in[5]};
    const float* Wf[4] = {(const float*)d_in[6], (const float*)d_in[8], (const float*)d_in[10], (const float*)d_in[12]};
    const float* bf[4] = {(const float*)d_in[7], (const float*)d_in[9], (const float*)d_in[11], (const float*)d_in[13]};
    const float* W4 = (const float*)d_in[14];
    const float* b4 = (const float*)d_in[15];
    const int* mn = (const int*)d_in[16];
    float* out = (float*)d_out;

    const int Kp[4] = {320, 1344, 832, 576};
    const int Msz[4] = {1024, 512, 256, 128};

    char* ws = (char*)d_ws;
    size_t off = 0;
    auto alloc = [&](size_t bytes) -> char* {
        char* p = ws + off;
        off = (off + bytes + 255) & ~(size_t)255;
        return p;
    };

    const size_t imgStride = (size_t)NV * HH * WWW * C2C;
    const size_t volStride = (size_t)NV * 32768 * C3C;

    unsigned short* Wb[4];
    for (int i = 0; i < 4; i++) Wb[i] = (unsigned short*)alloc((size_t)Msz[i] * Kp[i] * 2);
    unsigned short* imgT = (unsigned short*)alloc(2 * imgStride * 2);
    unsigned short* volT = (unsigned short*)alloc(2 * volStride * 2);
    size_t fixed = off;

    const size_t perPt = (size_t)NV * (2 * (CINP + 1024 + 512) + 8);
    int Nk = NPTS;
    if (fixed + (size_t)Nk * perPt + 4096 > ws_size) {
        size_t avail = (ws_size > fixed + 4096) ? (ws_size - fixed - 4096) : 0;
        long nk = (long)(avail / perPt);
        nk = (nk / 2048) * 2048;
        if (nk < 2048) nk = 2048;
        if (nk > NPTS) nk = NPTS;
        Nk = (int)nk;
    }
    unsigned short* ptT = (unsigned short*)alloc((size_t)NV * Nk * CINP * 2);
    unsigned short* o0 = (unsigned short*)alloc((size_t)NV * Nk * 1024 * 2);
    unsigned short* o1 = (unsigned short*)alloc((size_t)NV * Nk * 512 * 2);
    unsigned short* o2 = o0;  // alias: o0 dead once g2 runs
    float* dsum0 = (float*)alloc((size_t)NV * Nk * 4);
    float* dsum1 = (float*)alloc((size_t)NV * Nk * 4);

    k_prep<<<12000, 256, 0, stream>>>(Wf[0], Wf[1], Wf[2], Wf[3], Wb[0], Wb[1], Wb[2], Wb[3],
                                      img[0], img[1], imgT, imgStride, vol[0], vol[1], volT, volStride);

    for (int n0 = 0; n0 < NPTS; n0 += Nk) {
        int nk = NPTS - n0 < Nk ? NPTS - n0 : Nk;
        int NC = NV * nk;
        int nP256 = NC / 256;
        int nP128 = NC / 128;
        // level 0
        k_sampleL0<<<dim3(nk / 4, NV), 256, 0, stream>>>(pts, proj, imgT, volT, ptT, n0, nk);
        k_g0L0<<<4 * nP256, 512, 0, stream>>>(Wb[0], ptT, bf[0], o0);
        k_g1L0<<<2 * nP256, 512, 0, stream>>>(Wb[1], ptT, o0, bf[1], o1);
        k_g2L0<<<nP256, 512, 0, stream>>>(Wb[2], ptT, o1, bf[2], o2);
        k_g3L0<<<nP128, 256, 0, stream>>>(Wb[3], ptT, o2, bf[3], W4, dsum0);
        // level 1
        k_sampleL1<<<dim3(nk / 4, NV), 256, 0, stream>>>(pts, proj, imgT + imgStride, volT + volStride, ptT, n0, nk);
        k_g0L1<<<4 * nP256, 512, 0, stream>>>(Wb[0], ptT, bf[0], o0);
        k_g1L1<<<2 * nP256, 512, 0, stream>>>(Wb[1], ptT, o0, bf[1], o1);
        k_g2L1<<<nP256, 512, 0, stream>>>(Wb[2], ptT, o1, bf[2], o2);
        k_g3L1<<<nP128, 256, 0, stream>>>(Wb[3], ptT, o2, bf[3], W4, dsum1);
        // both levels
        k_fin2<<<dim3((nk + 255) / 256, 2), 256, 0, stream>>>(dsum0, dsum1, b4, mn, out, n0, nk);
    }
}